// Round 1
// baseline (807.157 us; speedup 1.0000x reference)
//
#include <hip/hip_runtime.h>

// HolonomyAttention: out = softmax_causal((Q @ C_h) K^T / sqrt(D)) V
// B=2 H=16 T=2048 D=64, fp32 in/out.
// Round 0: fused fp32 flash-attention baseline (no MFMA yet).

constexpr int Bc = 2;
constexpr int Hc = 16;
constexpr int Tc = 2048;
constexpr int Dc = 64;
constexpr int BQ = 64;          // Q rows per block
constexpr int NQB = Tc / BQ;    // 32
constexpr int STR = 68;         // padded LDS stride in floats (float4-aligned, low bank conflict)

__global__ __launch_bounds__(256, 2)
void holo_attn_kernel(const float* __restrict__ Qp,
                      const float* __restrict__ Kp,
                      const float* __restrict__ Vp,
                      const float* __restrict__ Cp,
                      float* __restrict__ Op)
{
    __shared__ float qrot[BQ * STR];
    __shared__ float kt[BQ * STR];   // also Q-tile staging in prologue
    __shared__ float vt[BQ * STR];
    __shared__ float pt[BQ * STR];   // also curvature staging in prologue

    const int t   = threadIdx.x;          // 0..255
    const int bh  = blockIdx.x >> 5;      // 0..31  (b*16 + h)
    const int qb  = blockIdx.x & (NQB - 1);
    const int h   = bh & (Hc - 1);
    const int q0  = qb * BQ;
    const int row = t >> 2;               // 0..63 : Q row owned by this thread
    const int g   = t & 3;                // 0..3  : quad lane within row

    const float* Qg = Qp + ((size_t)bh * Tc + q0) * Dc;
    const float* Kg = Kp + (size_t)bh * Tc * Dc;
    const float* Vg = Vp + (size_t)bh * Tc * Dc;
    const float* Cg = Cp + (size_t)h * Dc * Dc;

    // ---------- prologue: stage curvature -> pt, Q tile -> kt ----------
    #pragma unroll
    for (int kk = 0; kk < 4; ++kk) {
        const int flat = kk * 1024 + t * 4;      // 0..4095, coalesced float4
        const int r = flat >> 6, d = flat & 63;
        *(float4*)(&pt[r * STR + d]) = *(const float4*)(&Cg[flat]);
        *(float4*)(&kt[r * STR + d]) = *(const float4*)(&Qg[flat]);
    }
    __syncthreads();

    // qrot[row][e] for e in [g*16, g*16+16): sum_d Qtile[row][d] * C[d][e]
    {
        const int eb = g * 16;
        float4 a0 = {0,0,0,0}, a1 = {0,0,0,0}, a2 = {0,0,0,0}, a3 = {0,0,0,0};
        for (int d = 0; d < Dc; ++d) {
            const float qv = kt[row * STR + d];
            const float4 c0 = *(const float4*)(&pt[d * STR + eb + 0]);
            const float4 c1 = *(const float4*)(&pt[d * STR + eb + 4]);
            const float4 c2 = *(const float4*)(&pt[d * STR + eb + 8]);
            const float4 c3 = *(const float4*)(&pt[d * STR + eb + 12]);
            a0.x = fmaf(qv, c0.x, a0.x); a0.y = fmaf(qv, c0.y, a0.y);
            a0.z = fmaf(qv, c0.z, a0.z); a0.w = fmaf(qv, c0.w, a0.w);
            a1.x = fmaf(qv, c1.x, a1.x); a1.y = fmaf(qv, c1.y, a1.y);
            a1.z = fmaf(qv, c1.z, a1.z); a1.w = fmaf(qv, c1.w, a1.w);
            a2.x = fmaf(qv, c2.x, a2.x); a2.y = fmaf(qv, c2.y, a2.y);
            a2.z = fmaf(qv, c2.z, a2.z); a2.w = fmaf(qv, c2.w, a2.w);
            a3.x = fmaf(qv, c3.x, a3.x); a3.y = fmaf(qv, c3.y, a3.y);
            a3.z = fmaf(qv, c3.z, a3.z); a3.w = fmaf(qv, c3.w, a3.w);
        }
        *(float4*)(&qrot[row * STR + eb + 0])  = a0;
        *(float4*)(&qrot[row * STR + eb + 4])  = a1;
        *(float4*)(&qrot[row * STR + eb + 8])  = a2;
        *(float4*)(&qrot[row * STR + eb + 12]) = a3;
    }
    // qrot writes are protected by the __syncthreads at the top of the j-loop.

    float m_run = -1e30f, l_run = 0.0f;
    float o[16];
    #pragma unroll
    for (int i = 0; i < 16; ++i) o[i] = 0.0f;

    for (int j = 0; j <= qb; ++j) {
        __syncthreads();   // prev-iter pt/vt reads + prologue kt/pt reads done
        const int s0 = j * BQ;
        #pragma unroll
        for (int kk = 0; kk < 4; ++kk) {
            const int flat = kk * 1024 + t * 4;
            const int r = flat >> 6, d = flat & 63;
            *(float4*)(&kt[r * STR + d]) = *(const float4*)(&Kg[(size_t)s0 * Dc + flat]);
            *(float4*)(&vt[r * STR + d]) = *(const float4*)(&Vg[(size_t)s0 * Dc + flat]);
        }
        __syncthreads();

        // ---- scores: this thread owns cols c = g + 4*jj (interleaved => conflict-free K reads)
        float sc[16];
        #pragma unroll
        for (int jj = 0; jj < 16; ++jj) sc[jj] = 0.0f;
        for (int d4 = 0; d4 < 16; ++d4) {
            const float4 q4 = *(const float4*)(&qrot[row * STR + d4 * 4]);
            #pragma unroll
            for (int jj = 0; jj < 16; ++jj) {
                const int c = g + 4 * jj;
                const float4 k4 = *(const float4*)(&kt[c * STR + d4 * 4]);
                sc[jj] = fmaf(q4.x, k4.x, sc[jj]);
                sc[jj] = fmaf(q4.y, k4.y, sc[jj]);
                sc[jj] = fmaf(q4.z, k4.z, sc[jj]);
                sc[jj] = fmaf(q4.w, k4.w, sc[jj]);
            }
        }

        // ---- mask + scale + online softmax stats
        const float scale = 0.125f;   // 1/sqrt(64)
        float mt = -1e30f;
        if (j == qb) {  // diagonal tile: col (s0+c) attendable iff c <= row
            #pragma unroll
            for (int jj = 0; jj < 16; ++jj) {
                const int c = g + 4 * jj;
                sc[jj] = (c <= row) ? sc[jj] * scale : -1e30f;
                mt = fmaxf(mt, sc[jj]);
            }
        } else {
            #pragma unroll
            for (int jj = 0; jj < 16; ++jj) {
                sc[jj] *= scale;
                mt = fmaxf(mt, sc[jj]);
            }
        }
        mt = fmaxf(mt, __shfl_xor(mt, 1));
        mt = fmaxf(mt, __shfl_xor(mt, 2));
        const float m_new = fmaxf(m_run, mt);
        const float alpha = __expf(m_run - m_new);
        float lt = 0.0f;
        #pragma unroll
        for (int jj = 0; jj < 16; ++jj) {
            const float p = __expf(sc[jj] - m_new);
            lt += p;
            pt[row * STR + g + 4 * jj] = p;
        }
        lt += __shfl_xor(lt, 1);
        lt += __shfl_xor(lt, 2);
        l_run = l_run * alpha + lt;
        m_run = m_new;
        #pragma unroll
        for (int i = 0; i < 16; ++i) o[i] *= alpha;
        __syncthreads();   // P row fully visible before PV reads

        // ---- PV: this thread owns output dims [g*16, g*16+16) of its row
        const int ob = g * 16;
        for (int s4 = 0; s4 < 16; ++s4) {
            const float4 p4 = *(const float4*)(&pt[row * STR + s4 * 4]);
            const float pp[4] = {p4.x, p4.y, p4.z, p4.w};
            #pragma unroll
            for (int i = 0; i < 4; ++i) {
                const int s = s4 * 4 + i;
                const float pv = pp[i];
                const float4 v0 = *(const float4*)(&vt[s * STR + ob + 0]);
                const float4 v1 = *(const float4*)(&vt[s * STR + ob + 4]);
                const float4 v2 = *(const float4*)(&vt[s * STR + ob + 8]);
                const float4 v3 = *(const float4*)(&vt[s * STR + ob + 12]);
                o[0]  = fmaf(pv, v0.x, o[0]);  o[1]  = fmaf(pv, v0.y, o[1]);
                o[2]  = fmaf(pv, v0.z, o[2]);  o[3]  = fmaf(pv, v0.w, o[3]);
                o[4]  = fmaf(pv, v1.x, o[4]);  o[5]  = fmaf(pv, v1.y, o[5]);
                o[6]  = fmaf(pv, v1.z, o[6]);  o[7]  = fmaf(pv, v1.w, o[7]);
                o[8]  = fmaf(pv, v2.x, o[8]);  o[9]  = fmaf(pv, v2.y, o[9]);
                o[10] = fmaf(pv, v2.z, o[10]); o[11] = fmaf(pv, v2.w, o[11]);
                o[12] = fmaf(pv, v3.x, o[12]); o[13] = fmaf(pv, v3.y, o[13]);
                o[14] = fmaf(pv, v3.z, o[14]); o[15] = fmaf(pv, v3.w, o[15]);
            }
        }
    }

    // ---------- epilogue ----------
    const float inv_l = 1.0f / l_run;
    float* Og = Op + ((size_t)bh * Tc + q0 + row) * Dc + g * 16;
    #pragma unroll
    for (int jj4 = 0; jj4 < 4; ++jj4) {
        float4 r;
        r.x = o[jj4 * 4 + 0] * inv_l;
        r.y = o[jj4 * 4 + 1] * inv_l;
        r.z = o[jj4 * 4 + 2] * inv_l;
        r.w = o[jj4 * 4 + 3] * inv_l;
        *(float4*)(&Og[jj4 * 4]) = r;
    }
}

extern "C" void kernel_launch(void* const* d_in, const int* in_sizes, int n_in,
                              void* d_out, int out_size, void* d_ws, size_t ws_size,
                              hipStream_t stream) {
    const float* Q = (const float*)d_in[0];
    const float* K = (const float*)d_in[1];
    const float* V = (const float*)d_in[2];
    // d_in[3] = mask (tril, known analytically — unused)
    const float* C = (const float*)d_in[4];
    float* O = (float*)d_out;

    dim3 grid(Bc * Hc * NQB);   // 1024 blocks
    dim3 block(256);
    holo_attn_kernel<<<grid, block, 0, stream>>>(Q, K, V, C, O);
}

// Round 2
// 259.711 us; speedup vs baseline: 3.1079x; 3.1079x over previous
//
#include <hip/hip_runtime.h>

// HolonomyAttention: out = softmax_causal((Q @ C_h) K^T / sqrt(D)) V
// B=2 H=16 T=2048 D=64, fp32 in/out.
// Round 2: bf16 MFMA flash attention (16x16x32), fp32 softmax/accum.

typedef __attribute__((ext_vector_type(8))) short short8;  // 8 bf16 = 4 VGPRs
typedef __attribute__((ext_vector_type(4))) float f32x4;

constexpr int Tc  = 2048;
constexpr int Dc  = 64;
constexpr int BQ  = 64;          // rows per block / cols per K-tile
constexpr int NQB = Tc / BQ;     // 32
constexpr int LS  = 72;          // LDS row stride (bf16 elems): 144 B rows, b128-aligned

__device__ inline unsigned short f2bf(float f) {   // fp32 -> bf16 RNE
    union { float f; unsigned u; } x; x.f = f;
    unsigned r = (x.u + 0x7fffu + ((x.u >> 16) & 1u)) >> 16;
    return (unsigned short)r;
}

__global__ __launch_bounds__(256, 4)
void holo_attn_mfma(const float* __restrict__ Qp,
                    const float* __restrict__ Kp,
                    const float* __restrict__ Vp,
                    const float* __restrict__ Cp,
                    float* __restrict__ Op)
{
    __shared__ unsigned short qrot[BQ * LS];   // Q@C, bf16, [row][e]
    __shared__ unsigned short kt[BQ * LS];     // K tile natural [s][d]; prologue: Q tile
    __shared__ unsigned short vt[BQ * LS];     // V tile TRANSPOSED [d][s]; prologue: C^T [e][d]
    __shared__ unsigned short pt[BQ * LS];     // P tile natural [row][s]

    const int t    = threadIdx.x;
    const int lane = t & 63;
    const int wid  = t >> 6;         // 0..3
    const int l15  = lane & 15;
    const int quad = lane >> 4;      // 0..3
    const int wb   = wid * 16;       // wave's 16-row strip base within the 64-row Q tile

    // blockIdx -> (bh, qb); consecutive blocks alternate short/long q-tiles
    const int n   = blockIdx.x;
    const int bh  = n >> 5;                    // 0..31
    const int idx = n & 31;
    const int qb  = (idx & 1) ? (31 - (idx >> 1)) : (idx >> 1);
    const int h   = bh & 15;
    const int q0  = qb * BQ;

    const float* Qg = Qp + ((size_t)bh * Tc + q0) * Dc;
    const float* Kg = Kp + (size_t)bh * Tc * Dc;
    const float* Vg = Vp + (size_t)bh * Tc * Dc;
    const float* Cg = Cp + (size_t)h * Dc * Dc;

    // ---------------- prologue: stage Q (natural, ->kt) and C^T (->vt) ----------------
    #pragma unroll
    for (int kk = 0; kk < 4; ++kk) {
        const int flat = kk * 1024 + t * 4;    // coalesced float4
        const int r  = flat >> 6;              // row (Q: t-row; C: d)
        const int d0 = flat & 63;              // col (Q: d; C: e-base)
        float4 qv = *(const float4*)(&Qg[flat]);
        ushort4 qp;
        qp.x = f2bf(qv.x); qp.y = f2bf(qv.y); qp.z = f2bf(qv.z); qp.w = f2bf(qv.w);
        *(ushort4*)(&kt[r * LS + d0]) = qp;
        float4 cv = *(const float4*)(&Cg[flat]);
        vt[(d0 + 0) * LS + r] = f2bf(cv.x);    // ct[e][d]
        vt[(d0 + 1) * LS + r] = f2bf(cv.y);
        vt[(d0 + 2) * LS + r] = f2bf(cv.z);
        vt[(d0 + 3) * LS + r] = f2bf(cv.w);
    }
    __syncthreads();

    // Q_rot strip via MFMA: D[row][e], rows wb..wb+15
    {
        short8 a0 = *(const short8*)(&kt[(wb + l15) * LS + quad * 8]);
        short8 a1 = *(const short8*)(&kt[(wb + l15) * LS + 32 + quad * 8]);
        f32x4 qr[4];
        #pragma unroll
        for (int tn = 0; tn < 4; ++tn) {
            short8 b0 = *(const short8*)(&vt[(tn * 16 + l15) * LS + quad * 8]);
            short8 b1 = *(const short8*)(&vt[(tn * 16 + l15) * LS + 32 + quad * 8]);
            f32x4 c = {0.f, 0.f, 0.f, 0.f};
            c = __builtin_amdgcn_mfma_f32_16x16x32_bf16(a0, b0, c, 0, 0, 0);
            c = __builtin_amdgcn_mfma_f32_16x16x32_bf16(a1, b1, c, 0, 0, 0);
            qr[tn] = c;
        }
        #pragma unroll
        for (int tn = 0; tn < 4; ++tn)
            #pragma unroll
            for (int i = 0; i < 4; ++i)
                qrot[(wb + quad * 4 + i) * LS + tn * 16 + l15] = f2bf(qr[tn][i]);
        // qrot strip is written & read by this wave only; j-loop barrier orders it anyway
    }

    float m_run[4] = {-1e30f, -1e30f, -1e30f, -1e30f};
    float l_run[4] = {0.f, 0.f, 0.f, 0.f};
    f32x4 o[4];                                   // o[tn][i]: row wb+quad*4+i, d = tn*16+l15
    #pragma unroll
    for (int tn = 0; tn < 4; ++tn) o[tn] = f32x4{0.f, 0.f, 0.f, 0.f};

    for (int j = 0; j <= qb; ++j) {
        __syncthreads();   // prev-iter kt/vt (and prologue) reads complete before restage
        const float* Kb = Kg + (size_t)j * BQ * Dc;
        const float* Vb = Vg + (size_t)j * BQ * Dc;
        #pragma unroll
        for (int kk = 0; kk < 4; ++kk) {
            const int flat = kk * 1024 + t * 4;
            const int r  = flat >> 6;             // s
            const int d0 = flat & 63;             // d base
            float4 kv = *(const float4*)(&Kb[flat]);
            ushort4 kp;
            kp.x = f2bf(kv.x); kp.y = f2bf(kv.y); kp.z = f2bf(kv.z); kp.w = f2bf(kv.w);
            *(ushort4*)(&kt[r * LS + d0]) = kp;   // kt[s][d]
            float4 vv = *(const float4*)(&Vb[flat]);
            vt[(d0 + 0) * LS + r] = f2bf(vv.x);   // vt[d][s]  (transpose scatter)
            vt[(d0 + 1) * LS + r] = f2bf(vv.y);
            vt[(d0 + 2) * LS + r] = f2bf(vv.z);
            vt[(d0 + 3) * LS + r] = f2bf(vv.w);
        }
        __syncthreads();

        // ---- S = Qrot K^T (strip 16 x 64) ----
        short8 a0 = *(const short8*)(&qrot[(wb + l15) * LS + quad * 8]);
        short8 a1 = *(const short8*)(&qrot[(wb + l15) * LS + 32 + quad * 8]);
        f32x4 s[4];
        #pragma unroll
        for (int tn = 0; tn < 4; ++tn) {
            short8 b0 = *(const short8*)(&kt[(tn * 16 + l15) * LS + quad * 8]);
            short8 b1 = *(const short8*)(&kt[(tn * 16 + l15) * LS + 32 + quad * 8]);
            f32x4 c = {0.f, 0.f, 0.f, 0.f};
            c = __builtin_amdgcn_mfma_f32_16x16x32_bf16(a0, b0, c, 0, 0, 0);
            c = __builtin_amdgcn_mfma_f32_16x16x32_bf16(a1, b1, c, 0, 0, 0);
            s[tn] = c;
        }

        // ---- scale + causal mask ----
        const float scale = 0.125f;
        if (j == qb) {
            #pragma unroll
            for (int tn = 0; tn < 4; ++tn)
                #pragma unroll
                for (int i = 0; i < 4; ++i) {
                    const int row = wb + quad * 4 + i;
                    const int col = tn * 16 + l15;
                    s[tn][i] = (col <= row) ? s[tn][i] * scale : -1e30f;
                }
        } else {
            #pragma unroll
            for (int tn = 0; tn < 4; ++tn)
                #pragma unroll
                for (int i = 0; i < 4; ++i) s[tn][i] *= scale;
        }

        // ---- online softmax (row stats via 16-lane shfl groups) ----
        float alpha[4];
        #pragma unroll
        for (int i = 0; i < 4; ++i) {
            float v = fmaxf(fmaxf(s[0][i], s[1][i]), fmaxf(s[2][i], s[3][i]));
            v = fmaxf(v, __shfl_xor(v, 1));
            v = fmaxf(v, __shfl_xor(v, 2));
            v = fmaxf(v, __shfl_xor(v, 4));
            v = fmaxf(v, __shfl_xor(v, 8));
            const float mn = fmaxf(m_run[i], v);
            alpha[i] = __expf(m_run[i] - mn);
            m_run[i] = mn;
        }
        #pragma unroll
        for (int i = 0; i < 4; ++i) {
            float acc = 0.f;
            #pragma unroll
            for (int tn = 0; tn < 4; ++tn) {
                const float p = __expf(s[tn][i] - m_run[i]);
                s[tn][i] = p;
                acc += p;
            }
            acc += __shfl_xor(acc, 1);
            acc += __shfl_xor(acc, 2);
            acc += __shfl_xor(acc, 4);
            acc += __shfl_xor(acc, 8);
            l_run[i] = l_run[i] * alpha[i] + acc;
        }

        // ---- P -> LDS (C-layout -> natural), rescale O ----
        #pragma unroll
        for (int tn = 0; tn < 4; ++tn)
            #pragma unroll
            for (int i = 0; i < 4; ++i)
                pt[(wb + quad * 4 + i) * LS + tn * 16 + l15] = f2bf(s[tn][i]);
        #pragma unroll
        for (int tn = 0; tn < 4; ++tn)
            #pragma unroll
            for (int i = 0; i < 4; ++i) o[tn][i] *= alpha[i];

        __threadfence_block();   // order pt writes before same-wave A-frag reads

        // ---- O += P V ----
        short8 pa0 = *(const short8*)(&pt[(wb + l15) * LS + quad * 8]);
        short8 pa1 = *(const short8*)(&pt[(wb + l15) * LS + 32 + quad * 8]);
        #pragma unroll
        for (int tn = 0; tn < 4; ++tn) {
            short8 v0 = *(const short8*)(&vt[(tn * 16 + l15) * LS + quad * 8]);
            short8 v1 = *(const short8*)(&vt[(tn * 16 + l15) * LS + 32 + quad * 8]);
            o[tn] = __builtin_amdgcn_mfma_f32_16x16x32_bf16(pa0, v0, o[tn], 0, 0, 0);
            o[tn] = __builtin_amdgcn_mfma_f32_16x16x32_bf16(pa1, v1, o[tn], 0, 0, 0);
        }
    }

    // ---------------- epilogue ----------------
    #pragma unroll
    for (int i = 0; i < 4; ++i) {
        const float inv = 1.0f / l_run[i];
        const int row = q0 + wb + quad * 4 + i;
        float* dst = Op + ((size_t)bh * Tc + row) * Dc;
        #pragma unroll
        for (int tn = 0; tn < 4; ++tn)
            dst[tn * 16 + l15] = o[tn][i] * inv;
    }
}

extern "C" void kernel_launch(void* const* d_in, const int* in_sizes, int n_in,
                              void* d_out, int out_size, void* d_ws, size_t ws_size,
                              hipStream_t stream) {
    const float* Q = (const float*)d_in[0];
    const float* K = (const float*)d_in[1];
    const float* V = (const float*)d_in[2];
    // d_in[3] = causal mask (analytic — unused)
    const float* C = (const float*)d_in[4];
    float* O = (float*)d_out;

    dim3 grid(32 * NQB);   // 1024 blocks: (bh=2*16) x (qb=32)
    dim3 block(256);
    holo_attn_mfma<<<grid, block, 0, stream>>>(Q, K, V, C, O);
}

// Round 3
// 190.414 us; speedup vs baseline: 4.2390x; 1.3639x over previous
//
#include <hip/hip_runtime.h>

// HolonomyAttention: out = softmax_causal((Q @ C_h) K^T / sqrt(D)) V
// B=2 H=16 T=2048 D=64, fp32 in/out.
// Round 3: pre-pass (Qrot/K/V -> bf16, V transposed, XOR-swizzled tiles in ws)
//          + attention with global_load_lds double-buffered staging, BQ=128.

typedef __attribute__((ext_vector_type(8))) short short8;           // 8 bf16
typedef __attribute__((ext_vector_type(8))) unsigned short ushort8;
typedef __attribute__((ext_vector_type(4))) float f32x4;

constexpr int Tc  = 2048;
constexpr int Dc  = 64;
constexpr int BK  = 64;       // k-tile rows
constexpr int BQ  = 128;      // q rows per block (2 strips of 64)
constexpr int NKT = Tc / BK;  // 32 tiles per head
constexpr int LSP = 72;       // padded LDS stride (prepass bufs + pt)
constexpr size_t NELEM = (size_t)32 * Tc * Dc;   // elems per ws region (4,194,304)

__device__ inline unsigned short f2bf(float f) {   // fp32 -> bf16 RNE
    union { float f; unsigned u; } x; x.f = f;
    return (unsigned short)((x.u + 0x7fffu + ((x.u >> 16) & 1u)) >> 16);
}

// async 16B/lane global->LDS DMA; LDS dest = wave-uniform base + lane*16
__device__ inline void gl_lds16(const unsigned short* g, unsigned short* l) {
    __builtin_amdgcn_global_load_lds(
        (const __attribute__((address_space(1))) unsigned int*)g,
        (__attribute__((address_space(3))) unsigned int*)l,
        16, 0, 0);
}

// ---------------------------------------------------------------------------
// Pre-pass: per (bh, 64-row tile):
//   qrot_g[bh][t][e] = bf16( Q @ C_h )                (natural rows)
//   ksw_g tiles: [bh*32+st][s][ (cb ^ (s&7))*8 + d%8 ]  (swizzled 16B blocks)
//   vsw_g tiles: [bh*32+st][d][ (sb ^ (d&7))*8 + s%8 ]  (transposed + swizzled)
// ---------------------------------------------------------------------------
__global__ __launch_bounds__(256, 2)
void holo_prepass(const float* __restrict__ Qp, const float* __restrict__ Kp,
                  const float* __restrict__ Vp, const float* __restrict__ Cp,
                  unsigned short* __restrict__ qrot_g,
                  unsigned short* __restrict__ ksw_g,
                  unsigned short* __restrict__ vsw_g)
{
    __shared__ unsigned short qt[64 * LSP];   // Q tile natural [r][d]
    __shared__ unsigned short ct[64 * LSP];   // C^T [e][d]
    __shared__ unsigned short vs[64 * LSP];   // V tile natural [s][d]

    const int t = threadIdx.x, lane = t & 63, wid = t >> 6;
    const int l15 = lane & 15, quad = lane >> 4, wb = wid * 16;
    const int n = blockIdx.x, bh = n >> 5, st = n & 31, h = bh & 15;
    const int s0 = st * 64;

    const float* Qg = Qp + ((size_t)bh * Tc + s0) * Dc;
    const float* Kg = Kp + ((size_t)bh * Tc + s0) * Dc;
    const float* Vg = Vp + ((size_t)bh * Tc + s0) * Dc;
    const float* Cg = Cp + (size_t)h * Dc * Dc;
    const size_t tile = (size_t)(bh * 32 + st) * (BK * Dc);

    #pragma unroll
    for (int kk = 0; kk < 4; ++kk) {
        const int flat = kk * 1024 + t * 4;   // coalesced float4
        const int r = flat >> 6, d0 = flat & 63;
        float4 qv = *(const float4*)(&Qg[flat]);
        ushort4 qp; qp.x = f2bf(qv.x); qp.y = f2bf(qv.y); qp.z = f2bf(qv.z); qp.w = f2bf(qv.w);
        *(ushort4*)(&qt[r * LSP + d0]) = qp;
        float4 cv = *(const float4*)(&Cg[flat]);      // C[d=r][e=d0..d0+3] -> ct[e][d]
        ct[(d0 + 0) * LSP + r] = f2bf(cv.x);
        ct[(d0 + 1) * LSP + r] = f2bf(cv.y);
        ct[(d0 + 2) * LSP + r] = f2bf(cv.z);
        ct[(d0 + 3) * LSP + r] = f2bf(cv.w);
        float4 vv = *(const float4*)(&Vg[flat]);
        ushort4 vp; vp.x = f2bf(vv.x); vp.y = f2bf(vv.y); vp.z = f2bf(vv.z); vp.w = f2bf(vv.w);
        *(ushort4*)(&vs[r * LSP + d0]) = vp;
        // K: convert + swizzle straight to global (row r, col block cb -> cb^(r&7))
        float4 kv = *(const float4*)(&Kg[flat]);
        ushort4 kp; kp.x = f2bf(kv.x); kp.y = f2bf(kv.y); kp.z = f2bf(kv.z); kp.w = f2bf(kv.w);
        const int cb = d0 >> 3, sub = d0 & 7;
        *(ushort4*)(&ksw_g[tile + (size_t)r * Dc + (size_t)((cb ^ (r & 7)) * 8 + sub)]) = kp;
    }
    __syncthreads();

    // Q_rot strip via MFMA: rows wb..wb+15, D[row][e]
    {
        short8 a0 = *(const short8*)(&qt[(wb + l15) * LSP + quad * 8]);
        short8 a1 = *(const short8*)(&qt[(wb + l15) * LSP + 32 + quad * 8]);
        #pragma unroll
        for (int tn = 0; tn < 4; ++tn) {
            short8 b0 = *(const short8*)(&ct[(tn * 16 + l15) * LSP + quad * 8]);
            short8 b1 = *(const short8*)(&ct[(tn * 16 + l15) * LSP + 32 + quad * 8]);
            f32x4 c = {0.f, 0.f, 0.f, 0.f};
            c = __builtin_amdgcn_mfma_f32_16x16x32_bf16(a0, b0, c, 0, 0, 0);
            c = __builtin_amdgcn_mfma_f32_16x16x32_bf16(a1, b1, c, 0, 0, 0);
            #pragma unroll
            for (int i = 0; i < 4; ++i)
                qrot_g[((size_t)bh * Tc + s0 + wb + quad * 4 + i) * Dc + tn * 16 + l15] = f2bf(c[i]);
        }
    }

    // V transpose + swizzle: thread owns (d = t>>2, s-range g4*16..+16)
    {
        const int d = t >> 2, g4 = t & 3, x = d & 7;
        ushort8 b0, b1;
        #pragma unroll
        for (int i = 0; i < 8; ++i) b0[i] = vs[(g4 * 16 + i) * LSP + d];
        #pragma unroll
        for (int i = 0; i < 8; ++i) b1[i] = vs[(g4 * 16 + 8 + i) * LSP + d];
        *(ushort8*)(&vsw_g[tile + (size_t)d * Dc + (size_t)(((g4 * 2 + 0) ^ x) * 8)]) = b0;
        *(ushort8*)(&vsw_g[tile + (size_t)d * Dc + (size_t)(((g4 * 2 + 1) ^ x) * 8)]) = b1;
    }
}

// ---------------------------------------------------------------------------
// Attention: BQ=128 per block (4 waves x 2 strips of 16 rows), BK=64,
// double-buffered global_load_lds staging of swizzled bf16 tiles.
// ---------------------------------------------------------------------------
__global__ __launch_bounds__(256, 2)
void holo_attn3(const unsigned short* __restrict__ qrot_g,
                const unsigned short* __restrict__ ksw_g,
                const unsigned short* __restrict__ vsw_g,
                float* __restrict__ Op)
{
    __shared__ __align__(16) unsigned short kbuf[2][BK * Dc];   // swizzled [s][*]
    __shared__ __align__(16) unsigned short vbuf[2][BK * Dc];   // swizzled [d][*]
    __shared__ __align__(16) unsigned short pt[BQ * LSP];       // P natural, padded

    const int t = threadIdx.x, lane = t & 63, wid = t >> 6;
    const int l15 = lane & 15, quad = lane >> 4, wb = wid * 16, xp = l15 & 7;

    // work-balanced mapping: CU-pair gets qi and 15-qi
    const int n = blockIdx.x;
    int bh, qi;
    if (n < 256) { bh = n >> 4;              qi = n & 15; }
    else         { bh = 16 + ((n - 256) >> 4); qi = 15 - ((n - 256) & 15); }
    const int q0 = qi * BQ;
    const int jmax = 2 * qi + 1;

    // Q_rot A-fragments, kept in registers for the whole kernel
    const unsigned short* qg = qrot_g + ((size_t)bh * Tc + q0) * Dc;
    short8 qa[2][2];
    #pragma unroll
    for (int s2 = 0; s2 < 2; ++s2)
        #pragma unroll
        for (int kh = 0; kh < 2; ++kh)
            qa[s2][kh] = *(const short8*)(qg + (size_t)(s2 * 64 + wb + l15) * Dc + kh * 32 + quad * 8);

    // stage tile 0 into buffer 0
    {
        const unsigned short* kt_g = ksw_g + ((size_t)bh * NKT + 0) * (BK * Dc);
        const unsigned short* vt_g = vsw_g + ((size_t)bh * NKT + 0) * (BK * Dc);
        #pragma unroll
        for (int ii = 0; ii < 2; ++ii) {
            const int off = wid * 1024 + ii * 512;   // elems; 1 KiB per instruction
            gl_lds16(kt_g + off + lane * 8, &kbuf[0][off]);
            gl_lds16(vt_g + off + lane * 8, &vbuf[0][off]);
        }
    }

    float m_run[2][4], l_run[2][4];
    f32x4 o[2][4];
    #pragma unroll
    for (int s2 = 0; s2 < 2; ++s2)
        #pragma unroll
        for (int i = 0; i < 4; ++i) {
            m_run[s2][i] = -1e30f; l_run[s2][i] = 0.f;
            o[s2][i] = f32x4{0.f, 0.f, 0.f, 0.f};
        }

    const float scale = 0.125f;   // 1/sqrt(64)

    for (int j = 0; j <= jmax; ++j) {
        __syncthreads();          // drains DMA for buf[j&1]; all waves past prev compute
        const int cur = j & 1;
        if (j < jmax) {           // prefetch tile j+1 into the other buffer
            const unsigned short* kt_g = ksw_g + ((size_t)bh * NKT + j + 1) * (BK * Dc);
            const unsigned short* vt_g = vsw_g + ((size_t)bh * NKT + j + 1) * (BK * Dc);
            #pragma unroll
            for (int ii = 0; ii < 2; ++ii) {
                const int off = wid * 1024 + ii * 512;
                gl_lds16(kt_g + off + lane * 8, &kbuf[cur ^ 1][off]);
                gl_lds16(vt_g + off + lane * 8, &vbuf[cur ^ 1][off]);
            }
        }
        const bool act0 = (j < jmax);   // strip0 fully masked at j==jmax -> skip

        // ---- S = Qrot K^T ----
        f32x4 s[2][4];
        #pragma unroll
        for (int tn = 0; tn < 4; ++tn) {
            const int row = tn * 16 + l15;   // row&7 == xp
            short8 b0 = *(const short8*)(&kbuf[cur][row * Dc + ((quad     ) ^ xp) * 8]);
            short8 b1 = *(const short8*)(&kbuf[cur][row * Dc + ((4 + quad) ^ xp) * 8]);
            if (act0) {
                f32x4 c = {0.f, 0.f, 0.f, 0.f};
                c = __builtin_amdgcn_mfma_f32_16x16x32_bf16(qa[0][0], b0, c, 0, 0, 0);
                c = __builtin_amdgcn_mfma_f32_16x16x32_bf16(qa[0][1], b1, c, 0, 0, 0);
                s[0][tn] = c;
            }
            f32x4 c1 = {0.f, 0.f, 0.f, 0.f};
            c1 = __builtin_amdgcn_mfma_f32_16x16x32_bf16(qa[1][0], b0, c1, 0, 0, 0);
            c1 = __builtin_amdgcn_mfma_f32_16x16x32_bf16(qa[1][1], b1, c1, 0, 0, 0);
            s[1][tn] = c1;
        }

        // ---- mask + online softmax + P->LDS, per strip ----
        #pragma unroll
        for (int s2 = 0; s2 < 2; ++s2) {
            if (s2 == 0 && !act0) continue;
            const bool diag = (j >= 2 * qi + s2);
            if (diag) {
                #pragma unroll
                for (int tn = 0; tn < 4; ++tn)
                    #pragma unroll
                    for (int i = 0; i < 4; ++i) {
                        const int rowg = q0 + s2 * 64 + wb + quad * 4 + i;
                        const int colg = j * BK + tn * 16 + l15;
                        s[s2][tn][i] = (colg <= rowg) ? s[s2][tn][i] * scale : -1e30f;
                    }
            } else {
                #pragma unroll
                for (int tn = 0; tn < 4; ++tn)
                    #pragma unroll
                    for (int i = 0; i < 4; ++i) s[s2][tn][i] *= scale;
            }
            #pragma unroll
            for (int i = 0; i < 4; ++i) {
                float v = fmaxf(fmaxf(s[s2][0][i], s[s2][1][i]), fmaxf(s[s2][2][i], s[s2][3][i]));
                v = fmaxf(v, __shfl_xor(v, 1));
                v = fmaxf(v, __shfl_xor(v, 2));
                v = fmaxf(v, __shfl_xor(v, 4));
                v = fmaxf(v, __shfl_xor(v, 8));
                const float mn = fmaxf(m_run[s2][i], v);
                const float alpha = __expf(m_run[s2][i] - mn);
                m_run[s2][i] = mn;
                float acc = 0.f;
                #pragma unroll
                for (int tn = 0; tn < 4; ++tn) {
                    const float p = __expf(s[s2][tn][i] - mn);
                    s[s2][tn][i] = p;
                    acc += p;
                }
                acc += __shfl_xor(acc, 1);
                acc += __shfl_xor(acc, 2);
                acc += __shfl_xor(acc, 4);
                acc += __shfl_xor(acc, 8);
                l_run[s2][i] = l_run[s2][i] * alpha + acc;
                o[s2][0][i] *= alpha; o[s2][1][i] *= alpha;
                o[s2][2][i] *= alpha; o[s2][3][i] *= alpha;
            }
            #pragma unroll
            for (int tn = 0; tn < 4; ++tn)
                #pragma unroll
                for (int i = 0; i < 4; ++i)
                    pt[(s2 * 64 + wb + quad * 4 + i) * LSP + tn * 16 + l15] = f2bf(s[s2][tn][i]);
        }
        __threadfence_block();   // order wave-local pt writes before A-frag reads

        // ---- O += P V ----
        short8 pa[2][2];
        #pragma unroll
        for (int s2 = 0; s2 < 2; ++s2) {
            if (s2 == 0 && !act0) continue;
            pa[s2][0] = *(const short8*)(&pt[(s2 * 64 + wb + l15) * LSP + quad * 8]);
            pa[s2][1] = *(const short8*)(&pt[(s2 * 64 + wb + l15) * LSP + 32 + quad * 8]);
        }
        #pragma unroll
        for (int tn = 0; tn < 4; ++tn) {
            const int row = tn * 16 + l15;   // d index; row&7 == xp
            short8 v0 = *(const short8*)(&vbuf[cur][row * Dc + ((quad     ) ^ xp) * 8]);
            short8 v1 = *(const short8*)(&vbuf[cur][row * Dc + ((4 + quad) ^ xp) * 8]);
            if (act0) {
                o[0][tn] = __builtin_amdgcn_mfma_f32_16x16x32_bf16(pa[0][0], v0, o[0][tn], 0, 0, 0);
                o[0][tn] = __builtin_amdgcn_mfma_f32_16x16x32_bf16(pa[0][1], v1, o[0][tn], 0, 0, 0);
            }
            o[1][tn] = __builtin_amdgcn_mfma_f32_16x16x32_bf16(pa[1][0], v0, o[1][tn], 0, 0, 0);
            o[1][tn] = __builtin_amdgcn_mfma_f32_16x16x32_bf16(pa[1][1], v1, o[1][tn], 0, 0, 0);
        }
    }

    // ---- epilogue ----
    #pragma unroll
    for (int s2 = 0; s2 < 2; ++s2)
        #pragma unroll
        for (int i = 0; i < 4; ++i) {
            const float inv = 1.0f / l_run[s2][i];
            const int rowg = q0 + s2 * 64 + wb + quad * 4 + i;
            float* dst = Op + ((size_t)bh * Tc + rowg) * Dc;
            #pragma unroll
            for (int tn = 0; tn < 4; ++tn)
                dst[tn * 16 + l15] = o[s2][tn][i] * inv;
        }
}

extern "C" void kernel_launch(void* const* d_in, const int* in_sizes, int n_in,
                              void* d_out, int out_size, void* d_ws, size_t ws_size,
                              hipStream_t stream) {
    const float* Q = (const float*)d_in[0];
    const float* K = (const float*)d_in[1];
    const float* V = (const float*)d_in[2];
    // d_in[3] = causal mask (analytic — unused)
    const float* C = (const float*)d_in[4];
    float* O = (float*)d_out;

    unsigned short* qrot_w = (unsigned short*)d_ws;           // 8 MiB
    unsigned short* ksw_w  = qrot_w + NELEM;                  // 8 MiB
    unsigned short* vsw_w  = ksw_w + NELEM;                   // 8 MiB (total 24 MiB)

    holo_prepass<<<dim3(1024), dim3(256), 0, stream>>>(Q, K, V, C, qrot_w, ksw_w, vsw_w);
    holo_attn3<<<dim3(512), dim3(256), 0, stream>>>(qrot_w, ksw_w, vsw_w, O);
}